// Round 1
// baseline (2852.627 us; speedup 1.0000x reference)
//
#include <hip/hip_runtime.h>

#define NB 2
#define NN 100000
#define NF 64
#define NE 800000
#define EO 16
#define NO 64

// Edge stage: one thread per edge, both batches in-thread.
// h = sigmoid([x_src, x_tgt, ew] @ W_e + b_e); agg[tgt] += h; agg[src] -= h.
__global__ __launch_bounds__(256) void edge_kernel(
    const float* __restrict__ x, const int* __restrict__ esrc,
    const int* __restrict__ etgt, const float* __restrict__ ew,
    const float* __restrict__ We, const float* __restrict__ be,
    float* __restrict__ agg)
{
    int e = blockIdx.x * blockDim.x + threadIdx.x;
    if (e >= NE) return;
    int s = esrc[e];
    int t = etgt[e];
    float w = ew[e];

    float h0[EO], h1[EO];
#pragma unroll
    for (int k = 0; k < EO; ++k) {
        float base = be[k] + w * We[2 * NF * EO + k];  // row 128 = edge-weight row
        h0[k] = base;
        h1[k] = base;
    }

    const float* xs0 = x + (size_t)s * NF;
    const float* xt0 = x + (size_t)t * NF;
    const float* xs1 = xs0 + (size_t)NN * NF;
    const float* xt1 = xt0 + (size_t)NN * NF;

    for (int j = 0; j < NF; j += 4) {
        float4 as0 = *(const float4*)(xs0 + j);
        float4 at0 = *(const float4*)(xt0 + j);
        float4 as1 = *(const float4*)(xs1 + j);
        float4 at1 = *(const float4*)(xt1 + j);
        const float* ws = We + (size_t)j * EO;         // rows j..j+3      (src part)
        const float* wt = We + (size_t)(NF + j) * EO;  // rows 64+j..64+j+3 (tgt part)
#pragma unroll
        for (int jj = 0; jj < 4; ++jj) {
            float vs0 = ((const float*)&as0)[jj];
            float vt0 = ((const float*)&at0)[jj];
            float vs1 = ((const float*)&as1)[jj];
            float vt1 = ((const float*)&at1)[jj];
#pragma unroll
            for (int k = 0; k < EO; ++k) {
                float wsk = ws[jj * EO + k];  // wave-uniform -> s_load
                float wtk = wt[jj * EO + k];
                h0[k] += vs0 * wsk;
                h0[k] += vt0 * wtk;
                h1[k] += vs1 * wsk;
                h1[k] += vt1 * wtk;
            }
        }
    }

    float* at0p = agg + (size_t)t * EO;
    float* as0p = agg + (size_t)s * EO;
    float* at1p = at0p + (size_t)NN * EO;
    float* as1p = as0p + (size_t)NN * EO;
#pragma unroll
    for (int k = 0; k < EO; ++k) {
        float v0 = 1.0f / (1.0f + __expf(-h0[k]));
        float v1 = 1.0f / (1.0f + __expf(-h1[k]));
        unsafeAtomicAdd(at0p + k,  v0);   // hardware global_atomic_add_f32
        unsafeAtomicAdd(as0p + k, -v0);
        unsafeAtomicAdd(at1p + k,  v1);
        unsafeAtomicAdd(as1p + k, -v1);
    }
}

// Node stage: out = sigmoid(agg @ W_n + b_n). One 64-lane group per (b,n) row,
// lane = output channel.
__global__ __launch_bounds__(256) void node_kernel(
    const float* __restrict__ agg, const float* __restrict__ Wn,
    const float* __restrict__ bn, float* __restrict__ out)
{
    int row = blockIdx.x * 4 + (threadIdx.x >> 6);
    int c = threadIdx.x & 63;
    if (row >= NB * NN) return;
    const float* a = agg + (size_t)row * EO;
    float acc = bn[c];
#pragma unroll
    for (int k = 0; k < EO; ++k)
        acc += a[k] * Wn[k * NO + c];
    out[(size_t)row * NO + c] = 1.0f / (1.0f + __expf(-acc));
}

extern "C" void kernel_launch(void* const* d_in, const int* in_sizes, int n_in,
                              void* d_out, int out_size, void* d_ws, size_t ws_size,
                              hipStream_t stream) {
    const float* x    = (const float*)d_in[0];
    const int*   esrc = (const int*)d_in[1];
    const int*   etgt = (const int*)d_in[2];
    const float* ew   = (const float*)d_in[3];
    const float* We   = (const float*)d_in[4];
    const float* be   = (const float*)d_in[5];
    const float* Wn   = (const float*)d_in[6];
    const float* bn   = (const float*)d_in[7];
    float* out = (float*)d_out;
    float* agg = (float*)d_ws;  // NB*NN*EO floats = 12.8 MB

    hipMemsetAsync(agg, 0, (size_t)NB * NN * EO * sizeof(float), stream);
    edge_kernel<<<(NE + 255) / 256, 256, 0, stream>>>(x, esrc, etgt, ew, We, be, agg);
    node_kernel<<<(NB * NN + 3) / 4, 256, 0, stream>>>(agg, Wn, bn, out);
}

// Round 3
// 994.663 us; speedup vs baseline: 2.8679x; 2.8679x over previous
//
#include <hip/hip_runtime.h>

#define NB 2
#define NN 100000
#define NF 64
#define NE 800000
#define EO 16
#define NO 64

__device__ __forceinline__ float sigmoidf(float v) {
    return 1.0f / (1.0f + __expf(-v));
}

// Zero the agg accumulator (12.8 MB). Kernel-based so it is reliably part of
// the captured graph (runtime memset-in-capture was the prime suspect for the
// round-2 post-timing divergence).
__global__ __launch_bounds__(256) void zero_kernel(float4* __restrict__ p, int n4) {
    int i = blockIdx.x * blockDim.x + threadIdx.x;
    if (i < n4) p[i] = make_float4(0.f, 0.f, 0.f, 0.f);
}

// Edge stage: one thread per edge computes the 129->16 MLP for both batches.
// Scatter is transposed through LDS so 16 consecutive lanes write one dense
// 64B agg row per atomic instruction (4 lines/wave-instr instead of 64).
__global__ __launch_bounds__(256) void edge_kernel(
    const float* __restrict__ x, const int* __restrict__ esrc,
    const int* __restrict__ etgt, const float* __restrict__ ew,
    const float* __restrict__ We, const float* __restrict__ be,
    float* __restrict__ agg)
{
    __shared__ float hbuf[256 * EO];   // 16 KB
    __shared__ int snode[256];
    __shared__ int tnode[256];

    int tid = threadIdx.x;
    int e = blockIdx.x * 256 + tid;    // grid is exactly NE/256 blocks
    int s = esrc[e];
    int t = etgt[e];
    float w = ew[e];
    snode[tid] = s;
    tnode[tid] = t;

    float h0[EO], h1[EO];
#pragma unroll
    for (int k = 0; k < EO; ++k) {
        float base = be[k] + w * We[2 * NF * EO + k];  // row 128 = edge-weight row
        h0[k] = base;
        h1[k] = base;
    }

    const float* xs0 = x + (size_t)s * NF;
    const float* xt0 = x + (size_t)t * NF;
    const float* xs1 = xs0 + (size_t)NN * NF;
    const float* xt1 = xt0 + (size_t)NN * NF;

    for (int j = 0; j < NF; j += 4) {
        float4 as0 = *(const float4*)(xs0 + j);
        float4 at0 = *(const float4*)(xt0 + j);
        float4 as1 = *(const float4*)(xs1 + j);
        float4 at1 = *(const float4*)(xt1 + j);
        const float* ws = We + (size_t)j * EO;         // rows j..j+3      (src part)
        const float* wt = We + (size_t)(NF + j) * EO;  // rows 64+j..+3    (tgt part)
#pragma unroll
        for (int jj = 0; jj < 4; ++jj) {
            float vs0 = ((const float*)&as0)[jj];
            float vt0 = ((const float*)&at0)[jj];
            float vs1 = ((const float*)&as1)[jj];
            float vt1 = ((const float*)&at1)[jj];
#pragma unroll
            for (int k = 0; k < EO; ++k) {
                float wsk = ws[jj * EO + k];  // wave-uniform -> scalar loads
                float wtk = wt[jj * EO + k];
                h0[k] += vs0 * wsk;
                h0[k] += vt0 * wtk;
                h1[k] += vs1 * wsk;
                h1[k] += vt1 * wtk;
            }
        }
    }

    int g = tid >> 4;        // 16 groups of 16 lanes
    int k16 = tid & 15;

    // ---- batch 0: stage sigmoid(h0) in LDS, then coalesced scatter ----
#pragma unroll
    for (int k = 0; k < EO; ++k)
        hbuf[tid * EO + k] = sigmoidf(h0[k]);
    __syncthreads();
    {
        float* aggb = agg;   // batch 0
#pragma unroll
        for (int i = 0; i < 16; ++i) {
            int el = g + (i << 4);           // el mod 16 == g: each edge once
            float v = hbuf[el * EO + k16];
            int tt = tnode[el];
            int ss = snode[el];
            unsafeAtomicAdd(aggb + (size_t)tt * EO + k16,  v);
            unsafeAtomicAdd(aggb + (size_t)ss * EO + k16, -v);
        }
    }
    __syncthreads();

    // ---- batch 1 ----
#pragma unroll
    for (int k = 0; k < EO; ++k)
        hbuf[tid * EO + k] = sigmoidf(h1[k]);
    __syncthreads();
    {
        float* aggb = agg + (size_t)NN * EO;  // batch 1
#pragma unroll
        for (int i = 0; i < 16; ++i) {
            int el = g + (i << 4);
            float v = hbuf[el * EO + k16];
            int tt = tnode[el];
            int ss = snode[el];
            unsafeAtomicAdd(aggb + (size_t)tt * EO + k16,  v);
            unsafeAtomicAdd(aggb + (size_t)ss * EO + k16, -v);
        }
    }
}

// Node stage: out = sigmoid(agg @ W_n + b_n). 64 lanes per (b,n) row, lane=channel.
__global__ __launch_bounds__(256) void node_kernel(
    const float* __restrict__ agg, const float* __restrict__ Wn,
    const float* __restrict__ bn, float* __restrict__ out)
{
    int row = blockIdx.x * 4 + (threadIdx.x >> 6);
    int c = threadIdx.x & 63;
    if (row >= NB * NN) return;
    const float* a = agg + (size_t)row * EO;
    float acc = bn[c];
#pragma unroll
    for (int k = 0; k < EO; ++k)
        acc += a[k] * Wn[k * NO + c];
    out[(size_t)row * NO + c] = sigmoidf(acc);
}

extern "C" void kernel_launch(void* const* d_in, const int* in_sizes, int n_in,
                              void* d_out, int out_size, void* d_ws, size_t ws_size,
                              hipStream_t stream) {
    const float* x    = (const float*)d_in[0];
    const int*   esrc = (const int*)d_in[1];
    const int*   etgt = (const int*)d_in[2];
    const float* ew   = (const float*)d_in[3];
    const float* We   = (const float*)d_in[4];
    const float* be   = (const float*)d_in[5];
    const float* Wn   = (const float*)d_in[6];
    const float* bn   = (const float*)d_in[7];
    float* out = (float*)d_out;
    float* agg = (float*)d_ws;  // NB*NN*EO floats = 12.8 MB

    int n4 = NB * NN * EO / 4;  // 800000 float4s
    zero_kernel<<<(n4 + 255) / 256, 256, 0, stream>>>((float4*)agg, n4);
    edge_kernel<<<NE / 256, 256, 0, stream>>>(x, esrc, etgt, ew, We, be, agg);
    node_kernel<<<(NB * NN + 3) / 4, 256, 0, stream>>>(agg, Wn, bn, out);
}

// Round 4
// 350.727 us; speedup vs baseline: 8.1335x; 2.8360x over previous
//
#include <hip/hip_runtime.h>

#define NB 2
#define NN 100000
#define NF 64
#define NE 800000
#define EO 16
#define NO 64

__device__ __forceinline__ float sigmoidf(float v) {
    return 1.0f / (1.0f + __expf(-v));
}

// Zero the agg accumulator (12.8 MB). Kernel-based: runtime memset inside
// graph capture caused the round-2 post-timing divergence.
__global__ __launch_bounds__(256) void zero_kernel(float4* __restrict__ p, int n4) {
    int i = blockIdx.x * blockDim.x + threadIdx.x;
    if (i < n4) p[i] = make_float4(0.f, 0.f, 0.f, 0.f);
}

// Precompute: P1[b,n,:] = x[b,n,:] @ We[0:64]        (src half)
//             P2[b,n,:] = x[b,n,:] @ We[64:128] + be (tgt half + bias)
// One thread per (b,n) row; weights are wave-uniform -> scalar loads.
__global__ __launch_bounds__(256) void pre_kernel(
    const float* __restrict__ x, const float* __restrict__ We,
    const float* __restrict__ be, float* __restrict__ P1, float* __restrict__ P2)
{
    int r = blockIdx.x * 256 + threadIdx.x;
    if (r >= NB * NN) return;

    float a1[EO], a2[EO];
#pragma unroll
    for (int k = 0; k < EO; ++k) { a1[k] = 0.f; a2[k] = be[k]; }

    const float* row = x + (size_t)r * NF;
    for (int j = 0; j < NF; j += 4) {
        float4 v = *(const float4*)(row + j);
        const float* w1 = We + (size_t)j * EO;         // src-half rows
        const float* w2 = We + (size_t)(NF + j) * EO;  // tgt-half rows
#pragma unroll
        for (int jj = 0; jj < 4; ++jj) {
            float vv = ((const float*)&v)[jj];
#pragma unroll
            for (int k = 0; k < EO; ++k) {
                a1[k] += vv * w1[jj * EO + k];
                a2[k] += vv * w2[jj * EO + k];
            }
        }
    }
    float* p1 = P1 + (size_t)r * EO;
    float* p2 = P2 + (size_t)r * EO;
#pragma unroll
    for (int k = 0; k < EO; k += 4) {
        *(float4*)(p1 + k) = make_float4(a1[k], a1[k+1], a1[k+2], a1[k+3]);
        *(float4*)(p2 + k) = make_float4(a2[k], a2[k+1], a2[k+2], a2[k+3]);
    }
}

// Edge stage: h = sigmoid(P1[s] + P2[t] + w*We[128]). One thread per edge;
// per-row gather is now a single 64B line. Scatter transposed through LDS so
// 16 consecutive lanes write one dense 64B agg row per atomic instruction.
__global__ __launch_bounds__(256) void edge_kernel(
    const int* __restrict__ esrc, const int* __restrict__ etgt,
    const float* __restrict__ ew, const float* __restrict__ P1,
    const float* __restrict__ P2, const float* __restrict__ We,
    float* __restrict__ agg)
{
    __shared__ float hbuf[256 * EO];   // 16 KB
    __shared__ int snode[256];
    __shared__ int tnode[256];

    int tid = threadIdx.x;
    int e = blockIdx.x * 256 + tid;    // grid is exactly NE/256 blocks
    int s = esrc[e];
    int t = etgt[e];
    float w = ew[e];
    snode[tid] = s;
    tnode[tid] = t;

    int g = tid >> 4;
    int k16 = tid & 15;
    const float* wr = We + (size_t)2 * NF * EO;  // edge-weight row (row 128)

#pragma unroll
    for (int b = 0; b < NB; ++b) {
        const float* p1 = P1 + ((size_t)b * NN + s) * EO;
        const float* p2 = P2 + ((size_t)b * NN + t) * EO;
        float4 s0 = *(const float4*)(p1 + 0);
        float4 s1 = *(const float4*)(p1 + 4);
        float4 s2 = *(const float4*)(p1 + 8);
        float4 s3 = *(const float4*)(p1 + 12);
        float4 t0 = *(const float4*)(p2 + 0);
        float4 t1 = *(const float4*)(p2 + 4);
        float4 t2 = *(const float4*)(p2 + 8);
        float4 t3 = *(const float4*)(p2 + 12);
        const float* sa = (const float*)&s0;   // s0..s3 contiguous on stack? no -
        // safer: explicit per-vector handling
        float hs[EO];
        hs[0]=s0.x+t0.x; hs[1]=s0.y+t0.y; hs[2]=s0.z+t0.z; hs[3]=s0.w+t0.w;
        hs[4]=s1.x+t1.x; hs[5]=s1.y+t1.y; hs[6]=s1.z+t1.z; hs[7]=s1.w+t1.w;
        hs[8]=s2.x+t2.x; hs[9]=s2.y+t2.y; hs[10]=s2.z+t2.z; hs[11]=s2.w+t2.w;
        hs[12]=s3.x+t3.x; hs[13]=s3.y+t3.y; hs[14]=s3.z+t3.z; hs[15]=s3.w+t3.w;
        (void)sa;
#pragma unroll
        for (int k = 0; k < EO; ++k)
            hbuf[tid * EO + k] = sigmoidf(hs[k] + w * wr[k]);
        __syncthreads();

        float* aggb = agg + (size_t)b * NN * EO;
#pragma unroll
        for (int i = 0; i < 16; ++i) {
            int el = g + (i << 4);
            float v = hbuf[el * EO + k16];
            int tt = tnode[el];
            int ss = snode[el];
            unsafeAtomicAdd(aggb + (size_t)tt * EO + k16,  v);
            unsafeAtomicAdd(aggb + (size_t)ss * EO + k16, -v);
        }
        __syncthreads();
    }
}

// Node stage: out = sigmoid(agg @ W_n + b_n). 64 lanes per (b,n) row, lane=channel.
__global__ __launch_bounds__(256) void node_kernel(
    const float* __restrict__ agg, const float* __restrict__ Wn,
    const float* __restrict__ bn, float* __restrict__ out)
{
    int row = blockIdx.x * 4 + (threadIdx.x >> 6);
    int c = threadIdx.x & 63;
    if (row >= NB * NN) return;
    const float* a = agg + (size_t)row * EO;
    float acc = bn[c];
#pragma unroll
    for (int k = 0; k < EO; ++k)
        acc += a[k] * Wn[k * NO + c];
    out[(size_t)row * NO + c] = sigmoidf(acc);
}

extern "C" void kernel_launch(void* const* d_in, const int* in_sizes, int n_in,
                              void* d_out, int out_size, void* d_ws, size_t ws_size,
                              hipStream_t stream) {
    const float* x    = (const float*)d_in[0];
    const int*   esrc = (const int*)d_in[1];
    const int*   etgt = (const int*)d_in[2];
    const float* ew   = (const float*)d_in[3];
    const float* We   = (const float*)d_in[4];
    const float* be   = (const float*)d_in[5];
    const float* Wn   = (const float*)d_in[6];
    const float* bn   = (const float*)d_in[7];
    float* out = (float*)d_out;

    const size_t rows = (size_t)NB * NN;           // 200000
    float* agg = (float*)d_ws;                     // rows*EO floats = 12.8 MB
    float* P1  = agg + rows * EO;                  // 12.8 MB
    float* P2  = P1 + rows * EO;                   // 12.8 MB

    int n4 = (int)(rows * EO / 4);
    zero_kernel<<<(n4 + 255) / 256, 256, 0, stream>>>((float4*)agg, n4);
    pre_kernel<<<(int)((rows + 255) / 256), 256, 0, stream>>>(x, We, be, P1, P2);
    edge_kernel<<<NE / 256, 256, 0, stream>>>(esrc, etgt, ew, P1, P2, We, agg);
    node_kernel<<<(int)((rows + 3) / 4), 256, 0, stream>>>(agg, Wn, bn, out);
}

// Round 5
// 271.087 us; speedup vs baseline: 10.5229x; 1.2938x over previous
//
#include <hip/hip_runtime.h>
#include <hip/hip_fp16.h>

#define NB 2
#define NN 100000
#define NF 64
#define NE 800000
#define EO 16
#define NO 64
// agg / P layout is batch-interleaved: row n = [b0: 16 vals][b1: 16 vals]

__device__ __forceinline__ float sigmoidf(float v) {
    return 1.0f / (1.0f + __expf(-v));
}

// Precompute per node n (both batches):
//   P1[n][b][:] = x[b,n,:] @ We[0:64]         (src half)
//   P2[n][b][:] = x[b,n,:] @ We[64:128] + be  (tgt half + bias)
// Also zeroes the fp16 agg accumulator (runtime memset in capture is unsafe —
// round-2 lesson — and fusing here saves a dispatch).
__global__ __launch_bounds__(256) void pre_kernel(
    const float* __restrict__ x, const float* __restrict__ We,
    const float* __restrict__ be, float* __restrict__ P1,
    float* __restrict__ P2, float4* __restrict__ aggz)
{
    int n = blockIdx.x * 256 + threadIdx.x;
    if (n >= NN) return;

    // zero agg row n (NB*EO halves = 64 B = 4 float4)
    float4 z = make_float4(0.f, 0.f, 0.f, 0.f);
#pragma unroll
    for (int q = 0; q < 4; ++q) aggz[(size_t)n * 4 + q] = z;

#pragma unroll
    for (int b = 0; b < NB; ++b) {
        float a1[EO], a2[EO];
#pragma unroll
        for (int k = 0; k < EO; ++k) { a1[k] = 0.f; a2[k] = be[k]; }

        const float* row = x + ((size_t)b * NN + n) * NF;
        for (int j = 0; j < NF; j += 4) {
            float4 v = *(const float4*)(row + j);
            const float* w1 = We + (size_t)j * EO;
            const float* w2 = We + (size_t)(NF + j) * EO;
#pragma unroll
            for (int jj = 0; jj < 4; ++jj) {
                float vv = ((const float*)&v)[jj];
#pragma unroll
                for (int k = 0; k < EO; ++k) {
                    a1[k] += vv * w1[jj * EO + k];
                    a2[k] += vv * w2[jj * EO + k];
                }
            }
        }
        float* p1 = P1 + ((size_t)n * NB + b) * EO;
        float* p2 = P2 + ((size_t)n * NB + b) * EO;
#pragma unroll
        for (int k = 0; k < EO; k += 4) {
            *(float4*)(p1 + k) = make_float4(a1[k], a1[k+1], a1[k+2], a1[k+3]);
            *(float4*)(p2 + k) = make_float4(a2[k], a2[k+1], a2[k+2], a2[k+3]);
        }
    }
}

// Edge stage: h[b] = sigmoid(P1[s][b] + P2[t][b] + w*We[128]).
// Both batches are staged in LDS as half2, then scattered so that 16
// consecutive lanes cover one full 64 B agg row (both batches) with packed
// fp16 atomics: 25.6M lane-atomics / 1.6M line-RMWs (half of round 4 on both
// axes).
__global__ __launch_bounds__(256) void edge_kernel(
    const int* __restrict__ esrc, const int* __restrict__ etgt,
    const float* __restrict__ ew, const float* __restrict__ P1,
    const float* __restrict__ P2, const float* __restrict__ We,
    __half2* __restrict__ agg)
{
    __shared__ __half2 hbuf[256 * 17];   // row stride 17 -> conflict-free writes
    __shared__ int snode[256];
    __shared__ int tnode[256];

    int tid = threadIdx.x;
    int e = blockIdx.x * 256 + tid;      // grid exactly NE/256
    int s = esrc[e];
    int t = etgt[e];
    float w = ew[e];
    snode[tid] = s;
    tnode[tid] = t;

    const float* wr = We + (size_t)2 * NF * EO;  // edge-weight row

    float hs[NB * EO];
#pragma unroll
    for (int b = 0; b < NB; ++b) {
        const float* p1 = P1 + ((size_t)s * NB + b) * EO;
        const float* p2 = P2 + ((size_t)t * NB + b) * EO;
#pragma unroll
        for (int k = 0; k < EO; k += 4) {
            float4 sv = *(const float4*)(p1 + k);
            float4 tv = *(const float4*)(p2 + k);
            hs[b * EO + k + 0] = sigmoidf(sv.x + tv.x + w * wr[k + 0]);
            hs[b * EO + k + 1] = sigmoidf(sv.y + tv.y + w * wr[k + 1]);
            hs[b * EO + k + 2] = sigmoidf(sv.z + tv.z + w * wr[k + 2]);
            hs[b * EO + k + 3] = sigmoidf(sv.w + tv.w + w * wr[k + 3]);
        }
    }
#pragma unroll
    for (int j = 0; j < NB * EO / 2; ++j)   // j = b*8 + k8
        hbuf[tid * 17 + j] = __floats2half2_rn(hs[2 * j], hs[2 * j + 1]);
    __syncthreads();

    int g = tid >> 4;       // 16 groups of 16 lanes
    int k16 = tid & 15;     // half2 index within the 64 B agg row
#pragma unroll
    for (int i = 0; i < 16; ++i) {
        int el = g + (i << 4);
        __half2 v = hbuf[el * 17 + k16];
        int tt = tnode[el];
        int ss = snode[el];
        unsafeAtomicAdd(agg + (size_t)tt * 16 + k16, v);          // pk_add_f16
        unsafeAtomicAdd(agg + (size_t)ss * 16 + k16, __hneg2(v));
    }
}

// Node stage: out[b,n,:] = sigmoid(agg[n][b] @ W_n + b_n). 64 lanes per row,
// lane = output channel; agg reads are wave-uniform (scalarizable).
__global__ __launch_bounds__(256) void node_kernel(
    const __half* __restrict__ agg, const float* __restrict__ Wn,
    const float* __restrict__ bn, float* __restrict__ out)
{
    int row = blockIdx.x * 4 + (threadIdx.x >> 6);
    int c = threadIdx.x & 63;
    if (row >= NB * NN) return;
    int b = row >= NN;
    int n = row - b * NN;
    const __half* a = agg + ((size_t)n * NB + b) * EO;
    float acc = bn[c];
#pragma unroll
    for (int k = 0; k < EO; ++k)
        acc += __half2float(a[k]) * Wn[k * NO + c];
    out[(size_t)row * NO + c] = sigmoidf(acc);
}

extern "C" void kernel_launch(void* const* d_in, const int* in_sizes, int n_in,
                              void* d_out, int out_size, void* d_ws, size_t ws_size,
                              hipStream_t stream) {
    const float* x    = (const float*)d_in[0];
    const int*   esrc = (const int*)d_in[1];
    const int*   etgt = (const int*)d_in[2];
    const float* ew   = (const float*)d_in[3];
    const float* We   = (const float*)d_in[4];
    const float* be   = (const float*)d_in[5];
    const float* Wn   = (const float*)d_in[6];
    const float* bn   = (const float*)d_in[7];
    float* out = (float*)d_out;

    // ws layout: agg fp16 [NN][NB*EO] = 6.4 MB, then P1/P2 fp32 [NN][NB][EO]
    __half2* agg = (__half2*)d_ws;
    float* P1 = (float*)((char*)d_ws + (size_t)NN * NB * EO * sizeof(__half));
    float* P2 = P1 + (size_t)NN * NB * EO;

    pre_kernel<<<(NN + 255) / 256, 256, 0, stream>>>(x, We, be, P1, P2, (float4*)agg);
    edge_kernel<<<NE / 256, 256, 0, stream>>>(esrc, etgt, ew, P1, P2, We, agg);
    node_kernel<<<(NB * NN + 3) / 4, 256, 0, stream>>>((const __half*)agg, Wn, bn, out);
}

// Round 6
// 266.761 us; speedup vs baseline: 10.6936x; 1.0162x over previous
//
#include <hip/hip_runtime.h>
#include <hip/hip_fp16.h>

#define NB 2
#define NN 100000
#define NF 64
#define NE 800000
#define EO 16
#define NO 64
// agg / P layout is batch-interleaved: row n = [b0: 16 vals][b1: 16 vals]

__device__ __forceinline__ float sigmoidf(float v) {
    return 1.0f / (1.0f + __expf(-v));
}

// Precompute, one thread per (n,b) row-instance:
//   P1[n][b][:] = x[b,n,:] @ We[0:64]         (src half)
//   P2[n][b][:] = x[b,n,:] @ We[64:128] + be  (tgt half + bias)
// b==0 threads also zero the fp16 agg accumulator (runtime memset in capture
// is unsafe — round-2 lesson).
__global__ __launch_bounds__(256) void pre_kernel(
    const float* __restrict__ x, const float* __restrict__ We,
    const float* __restrict__ be, float* __restrict__ P1,
    float* __restrict__ P2, float4* __restrict__ aggz)
{
    int u = blockIdx.x * 256 + threadIdx.x;   // u = b*NN + n
    if (u >= NB * NN) return;
    int b = u >= NN;
    int n = u - b * NN;

    if (!b) {  // zero agg row n (64 B)
        float4 z = make_float4(0.f, 0.f, 0.f, 0.f);
#pragma unroll
        for (int q = 0; q < 4; ++q) aggz[(size_t)n * 4 + q] = z;
    }

    // hoist the x row into registers (64 VGPRs)
    float4 xv[16];
    const float* row = x + (size_t)u * NF;    // u == b*NN+n is exactly the row
#pragma unroll
    for (int j4 = 0; j4 < 16; ++j4) xv[j4] = *(const float4*)(row + 4 * j4);

    float a1[EO], a2[EO];
#pragma unroll
    for (int k = 0; k < EO; ++k) { a1[k] = 0.f; a2[k] = be[k]; }

#pragma unroll 4
    for (int j4 = 0; j4 < 16; ++j4) {
        const float* w1 = We + (size_t)(4 * j4) * EO;        // src-half rows
        const float* w2 = We + (size_t)(NF + 4 * j4) * EO;   // tgt-half rows
#pragma unroll
        for (int jj = 0; jj < 4; ++jj) {
            float vv = ((const float*)&xv[j4])[jj];
#pragma unroll
            for (int k = 0; k < EO; ++k) {
                a1[k] += vv * w1[jj * EO + k];   // uniform addr -> s_load
                a2[k] += vv * w2[jj * EO + k];
            }
        }
    }

    float* p1 = P1 + ((size_t)n * NB + b) * EO;
    float* p2 = P2 + ((size_t)n * NB + b) * EO;
#pragma unroll
    for (int k = 0; k < EO; k += 4) {
        *(float4*)(p1 + k) = make_float4(a1[k], a1[k+1], a1[k+2], a1[k+3]);
        *(float4*)(p2 + k) = make_float4(a2[k], a2[k+1], a2[k+2], a2[k+3]);
    }
}

// Edge stage (unchanged from round 5 — measured at the atomic-op ceiling):
// h[b] = sigmoid(P1[s][b] + P2[t][b] + w*We[128]); LDS-transposed scatter so
// 16 consecutive lanes cover one 64 B agg row with packed fp16 atomics.
__global__ __launch_bounds__(256) void edge_kernel(
    const int* __restrict__ esrc, const int* __restrict__ etgt,
    const float* __restrict__ ew, const float* __restrict__ P1,
    const float* __restrict__ P2, const float* __restrict__ We,
    __half2* __restrict__ agg)
{
    __shared__ __half2 hbuf[256 * 17];   // row stride 17 -> conflict-free writes
    __shared__ int snode[256];
    __shared__ int tnode[256];

    int tid = threadIdx.x;
    int e = blockIdx.x * 256 + tid;      // grid exactly NE/256
    int s = esrc[e];
    int t = etgt[e];
    float w = ew[e];
    snode[tid] = s;
    tnode[tid] = t;

    const float* wr = We + (size_t)2 * NF * EO;  // edge-weight row

    float hs[NB * EO];
#pragma unroll
    for (int b = 0; b < NB; ++b) {
        const float* p1 = P1 + ((size_t)s * NB + b) * EO;
        const float* p2 = P2 + ((size_t)t * NB + b) * EO;
#pragma unroll
        for (int k = 0; k < EO; k += 4) {
            float4 sv = *(const float4*)(p1 + k);
            float4 tv = *(const float4*)(p2 + k);
            hs[b * EO + k + 0] = sigmoidf(sv.x + tv.x + w * wr[k + 0]);
            hs[b * EO + k + 1] = sigmoidf(sv.y + tv.y + w * wr[k + 1]);
            hs[b * EO + k + 2] = sigmoidf(sv.z + tv.z + w * wr[k + 2]);
            hs[b * EO + k + 3] = sigmoidf(sv.w + tv.w + w * wr[k + 3]);
        }
    }
#pragma unroll
    for (int j = 0; j < NB * EO / 2; ++j)
        hbuf[tid * 17 + j] = __floats2half2_rn(hs[2 * j], hs[2 * j + 1]);
    __syncthreads();

    int g = tid >> 4;
    int k16 = tid & 15;
#pragma unroll
    for (int i = 0; i < 16; ++i) {
        int el = g + (i << 4);
        __half2 v = hbuf[el * 17 + k16];
        int tt = tnode[el];
        int ss = snode[el];
        unsafeAtomicAdd(agg + (size_t)tt * 16 + k16, v);          // pk_add_f16
        unsafeAtomicAdd(agg + (size_t)ss * 16 + k16, __hneg2(v));
    }
}

// Node stage: out[b,n,:] = sigmoid(agg[n][b] @ W_n + b_n).
// Thread = (row, 4 channels): Wn from LDS (ds_read_b128), agg row as 2x
// float4 broadcast loads, float4 stores (1 KB contiguous per wave-instr).
__global__ __launch_bounds__(256) void node_kernel(
    const float4* __restrict__ agg4, const float* __restrict__ Wn,
    const float* __restrict__ bn, float* __restrict__ out)
{
    __shared__ float wn[EO * NO];   // 4 KB, [k][c]
    int tid = threadIdx.x;
    *(float4*)(wn + tid * 4) = ((const float4*)Wn)[tid];  // 256*16B = 4KB exact
    __syncthreads();

    int u = blockIdx.x * 256 + tid;     // u over NB*NN*16 units, grid exact
    int row = u >> 4;                   // (b,n) row index, b-major
    int q = u & 15;                     // channel quad
    int b = row >= NN;
    int n = row - b * NN;

    // agg row for (n,b): 32 B = 2 float4 at interleaved offset
    const float4* ar = agg4 + ((size_t)n * NB + b) * 2;
    float4 rr[2];
    rr[0] = ar[0];
    rr[1] = ar[1];
    const __half2* hh = (const __half2*)rr;
    float a[EO];
#pragma unroll
    for (int i = 0; i < 8; ++i) {
        float2 f = __half22float2(hh[i]);
        a[2 * i] = f.x;
        a[2 * i + 1] = f.y;
    }

    float4 acc = *(const float4*)(bn + q * 4);
#pragma unroll
    for (int k = 0; k < EO; ++k) {
        float ak = a[k];
        float4 w = *(const float4*)(wn + k * NO + q * 4);  // 2-way alias: free
        acc.x += ak * w.x;
        acc.y += ak * w.y;
        acc.z += ak * w.z;
        acc.w += ak * w.w;
    }
    float4 o = make_float4(sigmoidf(acc.x), sigmoidf(acc.y),
                           sigmoidf(acc.z), sigmoidf(acc.w));
    *(float4*)(out + (size_t)row * NO + q * 4) = o;
}

extern "C" void kernel_launch(void* const* d_in, const int* in_sizes, int n_in,
                              void* d_out, int out_size, void* d_ws, size_t ws_size,
                              hipStream_t stream) {
    const float* x    = (const float*)d_in[0];
    const int*   esrc = (const int*)d_in[1];
    const int*   etgt = (const int*)d_in[2];
    const float* ew   = (const float*)d_in[3];
    const float* We   = (const float*)d_in[4];
    const float* be   = (const float*)d_in[5];
    const float* Wn   = (const float*)d_in[6];
    const float* bn   = (const float*)d_in[7];
    float* out = (float*)d_out;

    // ws layout: agg fp16 [NN][NB*EO] = 6.4 MB, then P1/P2 fp32 [NN][NB][EO]
    __half2* agg = (__half2*)d_ws;
    float* P1 = (float*)((char*)d_ws + (size_t)NN * NB * EO * sizeof(__half));
    float* P2 = P1 + (size_t)NN * NB * EO;

    pre_kernel<<<(NB * NN + 255) / 256, 256, 0, stream>>>(x, We, be, P1, P2,
                                                          (float4*)agg);
    edge_kernel<<<NE / 256, 256, 0, stream>>>(esrc, etgt, ew, P1, P2, We, agg);
    node_kernel<<<NB * NN * 16 / 256, 256, 0, stream>>>((const float4*)agg, Wn,
                                                        bn, out);
}

// Round 8
// 229.320 us; speedup vs baseline: 12.4395x; 1.1633x over previous
//
#include <hip/hip_runtime.h>
#include <hip/hip_fp16.h>

#define NB 2
#define NN 100000
#define NF 64
#define NE 800000
#define EO 16
#define NO 64
// agg layout: row n = [b0: 16 halves][b1: 16 halves]  (64 B, one line)
// P1h/P2h layout: row n = [b0: 16 halves][b1: 16 halves] (64 B, one line)

__device__ __forceinline__ float sigmoidf(float v) {
    return 1.0f / (1.0f + __expf(-v));
}

// Precompute, one thread per (n,b):
//   P1h[n][b][:] = fp16( x[b,n,:] @ We[0:64] )        (src half)
//   P2h[n][b][:] = fp16( x[b,n,:] @ We[64:128] + be ) (tgt half + bias)
// b==0 threads also zero the fp16 agg accumulator (kernel-based zeroing:
// runtime memset inside capture caused the round-2 post-timing divergence).
__global__ __launch_bounds__(256) void pre_kernel(
    const float* __restrict__ x, const float* __restrict__ We,
    const float* __restrict__ be, __half* __restrict__ P1h,
    __half* __restrict__ P2h, float4* __restrict__ aggz)
{
    int u = blockIdx.x * 256 + threadIdx.x;   // u = b*NN + n
    if (u >= NB * NN) return;
    int b = u >= NN;
    int n = u - b * NN;

    if (!b) {  // zero agg row n (64 B)
        float4 z = make_float4(0.f, 0.f, 0.f, 0.f);
#pragma unroll
        for (int q = 0; q < 4; ++q) aggz[(size_t)n * 4 + q] = z;
    }

    float a1[EO], a2[EO];
#pragma unroll
    for (int k = 0; k < EO; ++k) { a1[k] = 0.f; a2[k] = be[k]; }

    const float* row = x + (size_t)u * NF;    // u == b*NN+n is exactly the row
#pragma unroll 4
    for (int j4 = 0; j4 < 16; ++j4) {
        float4 v = *(const float4*)(row + 4 * j4);
        const float* w1 = We + (size_t)(4 * j4) * EO;        // src-half rows
        const float* w2 = We + (size_t)(NF + 4 * j4) * EO;   // tgt-half rows
#pragma unroll
        for (int jj = 0; jj < 4; ++jj) {
            float vv = ((const float*)&v)[jj];
#pragma unroll
            for (int k = 0; k < EO; ++k) {
                a1[k] += vv * w1[jj * EO + k];   // uniform addr -> scalarized
                a2[k] += vv * w2[jj * EO + k];
            }
        }
    }

    __half2 h1[8], h2[8];
#pragma unroll
    for (int i = 0; i < 8; ++i) {
        h1[i] = __floats2half2_rn(a1[2 * i], a1[2 * i + 1]);
        h2[i] = __floats2half2_rn(a2[2 * i], a2[2 * i + 1]);
    }
    __half* p1 = P1h + (size_t)n * (NB * EO) + b * EO;
    __half* p2 = P2h + (size_t)n * (NB * EO) + b * EO;
    *(float4*)(p1)     = ((float4*)h1)[0];
    *(float4*)(p1 + 8) = ((float4*)h1)[1];
    *(float4*)(p2)     = ((float4*)h2)[0];
    *(float4*)(p2 + 8) = ((float4*)h2)[1];
}

// Edge stage: h[b] = sigmoid(P1h[s][b] + P2h[t][b] + w*We[128]).
// Per edge: two 64 B line gathers (was four at fp32). LDS-transposed scatter:
// 16 consecutive lanes cover one 64 B agg row with packed fp16 atomics
// (25.6M pk-atomics — measured at the memory-side atomic-op ceiling, r4->r5
// scaling exactly 2x with op count).
__global__ __launch_bounds__(256) void edge_kernel(
    const int* __restrict__ esrc, const int* __restrict__ etgt,
    const float* __restrict__ ew, const __half* __restrict__ P1h,
    const __half* __restrict__ P2h, const float* __restrict__ We,
    __half2* __restrict__ agg)
{
    __shared__ __half2 hbuf[256 * 17];   // row stride 17 -> conflict-free writes
    __shared__ int snode[256];
    __shared__ int tnode[256];

    int tid = threadIdx.x;
    int e = blockIdx.x * 256 + tid;      // grid exactly NE/256
    int s = esrc[e];
    int t = etgt[e];
    float w = ew[e];
    snode[tid] = s;
    tnode[tid] = t;

    const float* wr = We + (size_t)2 * NF * EO;  // edge-weight row

    // load both 64 B P rows (one line each)
    float4 sv[4], tv[4];
    const float4* p1 = (const float4*)(P1h + (size_t)s * (NB * EO));
    const float4* p2 = (const float4*)(P2h + (size_t)t * (NB * EO));
#pragma unroll
    for (int i = 0; i < 4; ++i) { sv[i] = p1[i]; tv[i] = p2[i]; }

    const __half2* sh = (const __half2*)sv;   // 16 half2 = [b0 k0..15][b1 k0..15]
    const __half2* th = (const __half2*)tv;
    float hs[NB * EO];
#pragma unroll
    for (int i = 0; i < 16; ++i) {
        float2 fs = __half22float2(sh[i]);
        float2 ft = __half22float2(th[i]);
        hs[2 * i]     = sigmoidf(fs.x + ft.x + w * wr[(2 * i) & 15]);
        hs[2 * i + 1] = sigmoidf(fs.y + ft.y + w * wr[(2 * i + 1) & 15]);
    }
#pragma unroll
    for (int j = 0; j < NB * EO / 2; ++j)
        hbuf[tid * 17 + j] = __floats2half2_rn(hs[2 * j], hs[2 * j + 1]);
    __syncthreads();

    int g = tid >> 4;
    int k16 = tid & 15;
#pragma unroll
    for (int i = 0; i < 16; ++i) {
        int el = g + (i << 4);
        __half2 v = hbuf[el * 17 + k16];
        int tt = tnode[el];
        int ss = snode[el];
        unsafeAtomicAdd(agg + (size_t)tt * 16 + k16, v);          // pk_add_f16
        unsafeAtomicAdd(agg + (size_t)ss * 16 + k16, __hneg2(v));
    }
}

// Node stage: out[b,n,:] = sigmoid(agg[n][b] @ W_n + b_n).
// Thread = (row, 4 channels): Wn from LDS, agg row as 2x float4 broadcast,
// float4 stores (1 KB contiguous per wave-instr).
__global__ __launch_bounds__(256) void node_kernel(
    const float4* __restrict__ agg4, const float* __restrict__ Wn,
    const float* __restrict__ bn, float* __restrict__ out)
{
    __shared__ float wn[EO * NO];   // 4 KB, [k][c]
    int tid = threadIdx.x;
    *(float4*)(wn + tid * 4) = ((const float4*)Wn)[tid];  // 256*16B = 4KB exact
    __syncthreads();

    int u = blockIdx.x * 256 + tid;     // u over NB*NN*16 units, grid exact
    int row = u >> 4;                   // (b,n) row index, b-major
    int q = u & 15;                     // channel quad
    int b = row >= NN;
    int n = row - b * NN;

    const float4* ar = agg4 + ((size_t)n * NB + b) * 2;
    float4 rr0 = ar[0];
    float4 rr1 = ar[1];
    const __half2* hh0 = (const __half2*)&rr0;
    const __half2* hh1 = (const __half2*)&rr1;
    float a[EO];
#pragma unroll
    for (int i = 0; i < 4; ++i) {
        float2 f0 = __half22float2(hh0[i]);
        float2 f1 = __half22float2(hh1[i]);
        a[2 * i]         = f0.x;
        a[2 * i + 1]     = f0.y;
        a[8 + 2 * i]     = f1.x;
        a[8 + 2 * i + 1] = f1.y;
    }

    float4 acc = *(const float4*)(bn + q * 4);
#pragma unroll
    for (int k = 0; k < EO; ++k) {
        float ak = a[k];
        float4 wv = *(const float4*)(wn + k * NO + q * 4);  // 2-way alias: free
        acc.x += ak * wv.x;
        acc.y += ak * wv.y;
        acc.z += ak * wv.z;
        acc.w += ak * wv.w;
    }
    float4 o = make_float4(sigmoidf(acc.x), sigmoidf(acc.y),
                           sigmoidf(acc.z), sigmoidf(acc.w));
    *(float4*)(out + (size_t)row * NO + q * 4) = o;
}

extern "C" void kernel_launch(void* const* d_in, const int* in_sizes, int n_in,
                              void* d_out, int out_size, void* d_ws, size_t ws_size,
                              hipStream_t stream) {
    const float* x    = (const float*)d_in[0];
    const int*   esrc = (const int*)d_in[1];
    const int*   etgt = (const int*)d_in[2];
    const float* ew   = (const float*)d_in[3];
    const float* We   = (const float*)d_in[4];
    const float* be   = (const float*)d_in[5];
    const float* Wn   = (const float*)d_in[6];
    const float* bn   = (const float*)d_in[7];
    float* out = (float*)d_out;

    // ws layout: agg fp16 [NN][32] = 6.4 MB, P1h fp16 6.4 MB, P2h fp16 6.4 MB
    __half2* agg = (__half2*)d_ws;
    __half* P1h = (__half*)((char*)d_ws + (size_t)NN * NB * EO * sizeof(__half));
    __half* P2h = P1h + (size_t)NN * NB * EO;

    pre_kernel<<<(NB * NN + 255) / 256, 256, 0, stream>>>(x, We, be, P1h, P2h,
                                                          (float4*)agg);
    edge_kernel<<<NE / 256, 256, 0, stream>>>(esrc, etgt, ew, P1h, P2h, We, agg);
    node_kernel<<<NB * NN * 16 / 256, 256, 0, stream>>>((const float4*)agg, Wn,
                                                        bn, out);
}